// Round 19
// baseline (126.156 us; speedup 1.0000x reference)
//
#include <hip/hip_runtime.h>
#include <hip/hip_bf16.h>

// MTPAttention: B=2,S=2048,HS=1024,H=16,KV=4,DH=64, full attention + additive mask.
// Pipeline: prep(convert+weight-pack+mask-scan->d_out tail) -> GEMM(QKV,BM=32,BN=128,BK=64,
//           dbuf, 4 blocks/CU) + fused qk-norm -> V-transpose(sigma-permuted) ->
//           flash attn (R18 proven, 69.4us) -> GEMM(O@wo, same BM=32 shape).

typedef __attribute__((ext_vector_type(8))) short short8_t;   // 8 x bf16 (4 VGPR)
typedef __attribute__((ext_vector_type(4))) float f32x4_t;    // MFMA acc

__device__ __forceinline__ unsigned short f2bf_bits(float x) {
  unsigned int u = __float_as_uint(x);
  unsigned int r = u + 0x7fff + ((u >> 16) & 1);   // RNE (inputs finite)
  return (unsigned short)(r >> 16);
}
__device__ __forceinline__ float bf2f_bits(unsigned short b) {
  return __uint_as_float(((unsigned int)b) << 16);
}
__device__ __forceinline__ unsigned int cvt_pk_bf16(float lo, float hi) {
  unsigned int r;
  asm("v_cvt_pk_bf16_f32 %0, %1, %2" : "=v"(r) : "v"(lo), "v"(hi));
  return r;
}

__device__ __forceinline__ void async16(void* lds, const void* g) {
  __builtin_amdgcn_global_load_lds(
      (const __attribute__((address_space(1))) void*)g,
      (__attribute__((address_space(3))) void*)lds, 16, 0, 0);
}

// ------- prep: fused convert(hidden->bf16) + weight transpose-pack + mask bitmap/max -------
__global__ __launch_bounds__(256) void prep(
    const float* __restrict__ hidden, unsigned short* __restrict__ Xbf,
    const float* __restrict__ wq, const float* __restrict__ wk,
    const float* __restrict__ wv, const float* __restrict__ wo,
    unsigned short* __restrict__ Wqkvt, unsigned short* __restrict__ Wot,
    const float* __restrict__ mask, int* __restrict__ flags, float* __restrict__ tmax) {
  __shared__ unsigned short T[64][72];
  const int tid = threadIdx.x;
  int blk = blockIdx.x;
  if (blk < 4096) {                      // ---- convert ----
    int i = (blk * 256 + tid) * 4;
    float4 v = *(const float4*)(hidden + i);
    ushort4 o;
    o.x = f2bf_bits(v.x); o.y = f2bf_bits(v.y);
    o.z = f2bf_bits(v.z); o.w = f2bf_bits(v.w);
    *(ushort4*)(Xbf + i) = o;
    return;
  }
  if (blk < 4736) {                      // ---- weight pack ----
    int b = blk - 4096;
    const float* W; unsigned short* Wt; int Nsrc, n_off, bx, by;
    if (b < 256)      { W = wq; Wt = Wqkvt; Nsrc = 1024; n_off = 0;    bx = b & 15;         by = b >> 4; }
    else if (b < 320) { W = wk; Wt = Wqkvt; Nsrc = 256;  n_off = 1024; bx = (b - 256) & 3;  by = (b - 256) >> 2; }
    else if (b < 384) { W = wv; Wt = Wqkvt; Nsrc = 256;  n_off = 1280; bx = (b - 320) & 3;  by = (b - 320) >> 2; }
    else              { W = wo; Wt = Wot;   Nsrc = 1024; n_off = 0;    bx = (b - 384) & 15; by = (b - 384) >> 4; }
    const int tn = bx * 64, tk = by * 64;
    for (int e = tid; e < 4096; e += 256) {
      int kk = e >> 6, nn = e & 63;
      T[nn][kk] = f2bf_bits(W[(size_t)(tk + kk) * Nsrc + tn + nn]);
    }
    __syncthreads();
    for (int e = tid; e < 4096; e += 256) {
      int nn = e >> 6, kk = e & 63;
      Wt[(size_t)(n_off + tn + nn) * 1024 + tk + kk] = T[nn][kk];
    }
    return;
  }
  {                                      // ---- mask bitmap + per-tile max ----
    int mb = blk - 4736;
    const int bx = mb & 31, by = mb >> 5;
    const int bq = by * 64, bk = bx * 64, w = tid >> 6;
    bool nz = false;
    float vmax = -INFINITY;
    #pragma unroll
    for (int i = 0; i < 4; ++i) {
      int e = (i * 256 + tid) * 4;
      int r = e >> 6, c = e & 63;
      float4 v = *(const float4*)(mask + (size_t)(bq + r) * 2048 + bk + c);
      nz |= (v.x != 0.f) | (v.y != 0.f) | (v.z != 0.f) | (v.w != 0.f);
      vmax = fmaxf(vmax, fmaxf(fmaxf(v.x, v.y), fmaxf(v.z, v.w)));
    }
    #pragma unroll
    for (int m = 1; m < 64; m <<= 1) vmax = fmaxf(vmax, __shfl_xor(vmax, m, 64));
    unsigned long long anynz = __ballot((int)nz);
    __shared__ float wm[4];
    __shared__ int wf[4];
    if ((tid & 63) == 0) { wm[w] = vmax; wf[w] = (anynz != 0ull); }
    __syncthreads();
    if (tid == 0) {
      int idx = by * 32 + bx;
      flags[idx] = wf[0] | wf[1] | wf[2] | wf[3];
      tmax[idx] = fmaxf(fmaxf(wm[0], wm[1]), fmaxf(wm[2], wm[3]));
    }
  }
}

// ---- transpose V with sigma-permutation within each 64-block (zero-shuffle PV, 16x16):
//      k = 16n+4g+j  ->  k' = 32*(n>>1) + 8g + 4*(n&1) + j
__global__ __launch_bounds__(256) void transpose_v(
    const unsigned short* __restrict__ qkv, unsigned short* __restrict__ vt) {
  __shared__ unsigned short T[64][72];
  const int tid = threadIdx.x;
  const int st = blockIdx.x * 64, bk = blockIdx.y;      // bk = b*4+kvh
  const int b = bk >> 2, kvh = bk & 3;
  const unsigned short* src = qkv + (size_t)(b * 2048 + st) * 1536 + 1280 + kvh * 64;
  for (int e = tid; e < 4096; e += 256) {
    int s = e >> 6, d = e & 63;
    T[d][s] = src[(size_t)s * 1536 + d];                // coalesced read
  }
  __syncthreads();
  unsigned short* dst = vt + (size_t)bk * 64 * 2048 + st;
  for (int e = tid; e < 4096; e += 256) {
    int d = e >> 6, s = e & 63;
    int p = ((s >> 5) << 5) | (((s >> 2) & 3) << 3) | (((s >> 4) & 1) << 2) | (s & 3);
    dst[(size_t)d * 2048 + p] = T[d][s];                // 128B-contained permute
  }
}

// ------- bf16 GEMM (BM=32, BN=128, BK=64): dbuf single-barrier staging; 40 KB LDS ->
//         4 blocks/CU (16 waves/CU); conflict-free swizzle; XCD-swizzled -------
template <bool OUT_BF16, bool QKNORM>
__global__ __launch_bounds__(256) void gemm_bt(
    const unsigned short* __restrict__ A, const unsigned short* __restrict__ Bt,
    void* __restrict__ Cp, int M, int N, int K, int ldc,
    const float* __restrict__ qw, const float* __restrict__ kw) {
  __shared__ unsigned short As[2][32 * 64];    // 4 KB x2
  __shared__ unsigned short Bs[2][128 * 64];   // 16 KB x2
  const int tid = threadIdx.x;
  const int w = tid >> 6, l = tid & 63, lr = l & 15, lg = l >> 4;
  const int nwg = gridDim.x * gridDim.y;
  int orig = blockIdx.y * gridDim.x + blockIdx.x;
  int wgid = ((nwg & 7) == 0) ? ((orig & 7) * (nwg >> 3) + (orig >> 3)) : orig;
  const int bm = (wgid / gridDim.x) * 32, bn = (wgid % gridDim.x) * 128;
  const int wrow = (w >> 1) * 16, wcol = (w & 1) * 64;   // wave: 16 rows x 64 cols

  // per-lane staged-source pointers (advance by BK elements per stage call)
  const int rthr = tid >> 3;                      // 0..31
  const int qsw = (tid & 7) ^ (rthr & 7);         // lane-constant swizzled chunk
  const unsigned short* srcA = A + (size_t)(bm + rthr) * K + qsw * 8;   // 32 rows, 1 round
  const unsigned short* srcB[4];
  #pragma unroll
  for (int it = 0; it < 4; ++it)
    srcB[it] = Bt + (size_t)(bn + it * 32 + rthr) * K + qsw * 8;

  auto stage = [&](int bi) {
    async16(&As[bi][w * 512], srcA);
    srcA += 64;
    #pragma unroll
    for (int it = 0; it < 4; ++it) {
      async16(&Bs[bi][it * 2048 + w * 512], srcB[it]);
      srcB[it] += 64;
    }
  };

  stage(0);

  f32x4_t acc[4] = {};
  const int nst = K >> 6;

  #pragma unroll 2
  for (int st = 0; st < nst; ++st) {
    __syncthreads();   // drains vmcnt: buf[cur] ready; all waves done reading buf[cur^1]
    if (st + 1 < nst) stage((st + 1) & 1);
    const int cur = st & 1;
    #pragma unroll
    for (int kd = 0; kd < 2; ++kd) {
      short8_t af, bfr[4];
      {
        int r = wrow + lr;
        af = *(const short8_t*)(&As[cur][r * 64 + ((kd * 4 + lg) ^ (r & 7)) * 8]);
      }
      #pragma unroll
      for (int n = 0; n < 4; ++n) {
        int r = wcol + n * 16 + lr;
        bfr[n] = *(const short8_t*)(&Bs[cur][r * 64 + ((kd * 4 + lg) ^ (r & 7)) * 8]);
      }
      #pragma unroll
      for (int n = 0; n < 4; ++n)
        acc[n] = __builtin_amdgcn_mfma_f32_16x16x32_bf16(af, bfr[n], acc[n], 0, 0, 0);
    }
  }

  if constexpr (QKNORM) {
    int seg = (bn + wcol) >> 6;               // wave holds full 64-col head segment
    if (seg < 20) {
      const float* wseg = (seg < 16) ? qw : kw;
      float wv[4];
      #pragma unroll
      for (int n = 0; n < 4; ++n) {
        wv[n] = wseg[n * 16 + lr];
        if (seg < 16) wv[n] *= 0.125f;
      }
      #pragma unroll
      for (int j = 0; j < 4; ++j) {
        float ss = acc[0][j] * acc[0][j];
        #pragma unroll
        for (int n = 1; n < 4; ++n) ss += acc[n][j] * acc[n][j];
        #pragma unroll
        for (int x = 1; x < 16; x <<= 1) ss += __shfl_xor(ss, x, 64);
        float rinv = rsqrtf(ss * (1.0f / 64.0f) + 1e-6f);
        #pragma unroll
        for (int n = 0; n < 4; ++n) acc[n][j] *= rinv * wv[n];
      }
    }
  }

  #pragma unroll
  for (int n = 0; n < 4; ++n)
    #pragma unroll
    for (int j = 0; j < 4; ++j) {
      int row = bm + wrow + lg * 4 + j;
      int col = bn + wcol + n * 16 + lr;
      float v = acc[n][j];
      if (OUT_BF16) ((unsigned short*)Cp)[(size_t)row * ldc + col] = f2bf_bits(v);
      else          ((float*)Cp)[(size_t)row * ldc + col] = v;
    }
}

// ------- flash attention (R18 proven, 69.4us): frozen verbatim -------
__global__ __launch_bounds__(256, 4) void flash_attn(
    const unsigned short* __restrict__ qkv, const unsigned short* __restrict__ vtg,
    const float* __restrict__ mask, const int* __restrict__ flags,
    const float* __restrict__ tmax, const float* __restrict__ qw,
    const float* __restrict__ kw, unsigned short* __restrict__ O) {
  // grid is 32x32 = 1024 blocks; swizzle so each XCD gets 4 consecutive bh strips
  int orig = blockIdx.y * 32 + blockIdx.x;
  int swz = (orig & 7) * 128 + (orig >> 3);
  const int qt = swz & 31, bh = swz >> 5;
  const int b = bh >> 4, hq = bh & 15, kvh = hq >> 2;
  const int tid = threadIdx.x, w = tid >> 6, l = tid & 63, lr = l & 15, lg = l >> 4;

  // linear LDS + XOR swizzle (16B units): LDS(row, cc) holds global(row, cc ^ (row&7))
  __shared__ unsigned short Ks[2][64 * 64];   // [k][d]   8KB x2
  __shared__ unsigned short Vs[2][64 * 64];   // [d][k']  8KB x2 (k' sigma-permuted)

  const unsigned short* Qg = qkv + (size_t)(b * 2048 + qt * 64) * 1536 + hq * 64;
  const unsigned short* Kg = qkv + (size_t)(b * 2048) * 1536 + 1024 + kvh * 64;
  const unsigned short* Vg = vtg + (size_t)(b * 4 + kvh) * 64 * 2048;
  const float* Mg = mask + (size_t)(qt * 64) * 2048;
  const int* Fp = flags + qt * 32;

  auto stage = [&](int kt2, int bi) {
    #pragma unroll
    for (int it = 0; it < 2; ++it) {
      int c = it * 256 + tid;                    // 16B chunk id 0..511
      int r = c >> 3, cc = (c & 7) ^ (r & 7);    // pre-swizzled source column
      async16(&Ks[bi][it * 2048 + w * 512],
              Kg + (size_t)(kt2 * 64 + r) * 1536 + cc * 8);
      async16(&Vs[bi][it * 2048 + w * 512],
              Vg + (size_t)r * 2048 + kt2 * 64 + cc * 8);
    }
  };

  stage(0, 0);

  // a-priori bound: s <= 8*max_d|qw_d*kw_d| (Cauchy-Schwarz on RMS-normalized q,k with
  // the 0.125 scale folded into qw) + max over this strip's mask tiles.
  const float L2E = 1.44269504f;
  float pmax = fabsf(qw[l] * kw[l]);
  #pragma unroll
  for (int m = 1; m < 64; m <<= 1) pmax = fmaxf(pmax, __shfl_xor(pmax, m, 64));
  float tmx = (l < 32) ? tmax[qt * 32 + l] : -INFINITY;
  #pragma unroll
  for (int m = 1; m < 64; m <<= 1) tmx = fmaxf(tmx, __shfl_xor(tmx, m, 64));
  const float nm = -(8.0f * pmax + fmaxf(tmx, 0.0f)) * L2E;

  // Q fragments straight from global (once per block): wave w owns rows w*16..w*16+15
  short8_t qf[2];
  {
    const unsigned short* qrow = Qg + (size_t)(w * 16 + lr) * 1536 + lg * 8;
    qf[0] = *(const short8_t*)(qrow);
    qf[1] = *(const short8_t*)(qrow + 32);
  }

  // constant ones B-fragment: col 0 = 1.0 -> sum column
  short8_t vb1;
  #pragma unroll
  for (int e = 0; e < 8; ++e) vb1[e] = (lr == 0) ? (short)0x3f80 : (short)0;

  f32x4_t oacc[5] = {};                          // [0..3]=O cols, [4]=row-sum col

  #pragma unroll 2
  for (int kt = 0; kt < 32; ++kt) {
    __syncthreads();                             // buf ready (vmcnt drained), prev reads done
    if (kt < 31) stage(kt + 1, (kt + 1) & 1);
    const int cur = kt & 1;

    // S^T = K Q^T (swapped operands; scale pre-folded into Q).
    // sacc[n][j] = S[k = kt*64 + n*16 + lg*4 + j][q = qt*64 + w*16 + lr]
    f32x4_t sacc[4] = {};
    __builtin_amdgcn_s_setprio(1);
    #pragma unroll
    for (int kd = 0; kd < 2; ++kd)
      #pragma unroll
      for (int n = 0; n < 4; ++n) {
        int kr = n * 16 + lr;
        short8_t kf = *(const short8_t*)(&Ks[cur][kr * 64 + ((kd * 4 + lg) ^ (kr & 7)) * 8]);
        sacc[n] = __builtin_amdgcn_mfma_f32_16x16x32_bf16(kf, qf[kd], sacc[n], 0, 0, 0);
      }
    __builtin_amdgcn_s_setprio(0);

    // exp straight off sacc (fixed bound): lane holds P[q=lr][k=16n+4lg+j] -> exactly the
    // PV A-frag at k' = 32*(n>>1) + 8*lg + 4*(n&1) + j (V was sigma-permuted to match).
    const bool hasmask = Fp[kt] != 0;
    float e4[4][4];
    #pragma unroll
    for (int n = 0; n < 4; ++n) {
      if (hasmask) {
        float4 mv = *(const float4*)(Mg + (size_t)(w * 16 + lr) * 2048 + kt * 64 + n * 16 + lg * 4);
        e4[n][0] = exp2f(fmaf(sacc[n][0] + mv.x, L2E, nm));
        e4[n][1] = exp2f(fmaf(sacc[n][1] + mv.y, L2E, nm));
        e4[n][2] = exp2f(fmaf(sacc[n][2] + mv.z, L2E, nm));
        e4[n][3] = exp2f(fmaf(sacc[n][3] + mv.w, L2E, nm));
      } else {
        #pragma unroll
        for (int j = 0; j < 4; ++j)
          e4[n][j] = exp2f(fmaf(sacc[n][j], L2E, nm));
      }
    }
    short8_t pa[2];
    #pragma unroll
    for (int kd = 0; kd < 2; ++kd) {
      int4 pk;
      pk.x = (int)cvt_pk_bf16(e4[2 * kd][0],     e4[2 * kd][1]);
      pk.y = (int)cvt_pk_bf16(e4[2 * kd][2],     e4[2 * kd][3]);
      pk.z = (int)cvt_pk_bf16(e4[2 * kd + 1][0], e4[2 * kd + 1][1]);
      pk.w = (int)cvt_pk_bf16(e4[2 * kd + 1][2], e4[2 * kd + 1][3]);
      pa[kd] = *(short8_t*)&pk;
    }

    // O += P V (+ ones column -> running sum); zero-shuffle A-frags
    __builtin_amdgcn_s_setprio(1);
    #pragma unroll
    for (int kd = 0; kd < 2; ++kd) {
      #pragma unroll
      for (int nd = 0; nd < 4; ++nd) {
        int vr = nd * 16 + lr;
        short8_t vb = *(const short8_t*)(&Vs[cur][vr * 64 + ((kd * 4 + lg) ^ (vr & 7)) * 8]);
        oacc[nd] = __builtin_amdgcn_mfma_f32_16x16x32_bf16(pa[kd], vb, oacc[nd], 0, 0, 0);
      }
      oacc[4] = __builtin_amdgcn_mfma_f32_16x16x32_bf16(pa[kd], vb1, oacc[4], 0, 0, 0);
    }
    __builtin_amdgcn_s_setprio(0);
  }

  // epilogue: O[q = qt*64 + w*16 + lg*4 + j][d = hq*64 + nd*16 + lr]; sums in lanes lr==0
  float rln[4];
  #pragma unroll
  for (int j = 0; j < 4; ++j) rln[j] = 1.0f / __shfl(oacc[4][j], l & 48, 64);
  #pragma unroll
  for (int nd = 0; nd < 4; ++nd)
    #pragma unroll
    for (int j = 0; j < 4; ++j) {
      size_t row = (size_t)(b * 2048 + qt * 64 + w * 16 + lg * 4 + j);
      O[row * 1024 + hq * 64 + nd * 16 + lr] = f2bf_bits(oacc[nd][j] * rln[j]);
    }
}

extern "C" void kernel_launch(void* const* d_in, const int* in_sizes, int n_in,
                              void* d_out, int out_size, void* d_ws, size_t ws_size,
                              hipStream_t stream) {
  const float* hidden = (const float*)d_in[0];
  const float* mask   = (const float*)d_in[1];
  const float* wq     = (const float*)d_in[2];
  const float* wk     = (const float*)d_in[3];
  const float* wv     = (const float*)d_in[4];
  const float* wo     = (const float*)d_in[5];
  const float* qw     = (const float*)d_in[6];
  const float* kw     = (const float*)d_in[7];

  char* ws = (char*)d_ws;
  unsigned short* Xbf   = (unsigned short*)(ws);              // [4096][1024] bf16
  unsigned short* Wqkvt = (unsigned short*)(ws +  8388608);   // [1536][1024] bf16 (dead after gemm1)
  unsigned short* Wot   = (unsigned short*)(ws + 11534336);   // [1024][1024] bf16
  unsigned short* QKV   = (unsigned short*)(ws + 13631488);   // [4096][1536] bf16
  unsigned short* Vtg   = Wqkvt;                              // [8*64][2048] bf16 (ends 10485760)
  unsigned short* Obf   = Xbf;                                // X dead after gemm1

  // flags/tmax in the TAIL of d_out: written by prep, read by flash, then gemm2
  // overwrites all of d_out last.
  char* dtail = (char*)d_out + (size_t)out_size * 4 - 8192;
  int*   flags = (int*)dtail;                                 // [1024]
  float* tmaxb = (float*)(dtail + 4096);                      // [1024]

  prep<<<5760, 256, 0, stream>>>(hidden, Xbf, wq, wk, wv, wo, Wqkvt, Wot, mask, flags, tmaxb);

  gemm_bt<true, true><<<dim3(12, 128), 256, 0, stream>>>(
      Xbf, Wqkvt, QKV, 4096, 1536, 1024, 1536, qw, kw);
  transpose_v<<<dim3(32, 8), 256, 0, stream>>>(QKV, Vtg);      // after gemm1 (aliases Wqkvt)
  flash_attn<<<dim3(32, 32), 256, 0, stream>>>(QKV, Vtg, mask, flags, tmaxb, qw, kw, Obf);
  gemm_bt<false, false><<<dim3(8, 128), 256, 0, stream>>>(
      Obf, Wot, d_out, 4096, 1024, 1024, 1024, nullptr, nullptr);
}

// Round 20
// 117.194 us; speedup vs baseline: 1.0765x; 1.0765x over previous
//
#include <hip/hip_runtime.h>
#include <hip/hip_bf16.h>

// MTPAttention: B=2,S=2048,HS=1024,H=16,KV=4,DH=64, full attention + additive mask.
// Pipeline: prep(convert+weight-pack+mask-scan->d_out tail) -> GEMM(QKV,BM=64,BN=128,BK=64,
//           dbuf single-barrier, swizzled) + fused qk-norm -> V-transpose(sigma-permuted) ->
//           flash attn (R18 proven, 69.4us) -> GEMM(O@wo, BM=64,BN=64).
// R19 lesson: BM=32 doubles B-panel traffic -> regression; BM=64 is the traffic/TLP optimum.

typedef __attribute__((ext_vector_type(8))) short short8_t;   // 8 x bf16 (4 VGPR)
typedef __attribute__((ext_vector_type(4))) float f32x4_t;    // MFMA acc

__device__ __forceinline__ unsigned short f2bf_bits(float x) {
  unsigned int u = __float_as_uint(x);
  unsigned int r = u + 0x7fff + ((u >> 16) & 1);   // RNE (inputs finite)
  return (unsigned short)(r >> 16);
}
__device__ __forceinline__ float bf2f_bits(unsigned short b) {
  return __uint_as_float(((unsigned int)b) << 16);
}
__device__ __forceinline__ unsigned int cvt_pk_bf16(float lo, float hi) {
  unsigned int r;
  asm("v_cvt_pk_bf16_f32 %0, %1, %2" : "=v"(r) : "v"(lo), "v"(hi));
  return r;
}

__device__ __forceinline__ void async16(void* lds, const void* g) {
  __builtin_amdgcn_global_load_lds(
      (const __attribute__((address_space(1))) void*)g,
      (__attribute__((address_space(3))) void*)lds, 16, 0, 0);
}

// ------- prep: fused convert(hidden->bf16) + weight transpose-pack + mask bitmap/max -------
__global__ __launch_bounds__(256) void prep(
    const float* __restrict__ hidden, unsigned short* __restrict__ Xbf,
    const float* __restrict__ wq, const float* __restrict__ wk,
    const float* __restrict__ wv, const float* __restrict__ wo,
    unsigned short* __restrict__ Wqkvt, unsigned short* __restrict__ Wot,
    const float* __restrict__ mask, int* __restrict__ flags, float* __restrict__ tmax) {
  __shared__ unsigned short T[64][72];
  const int tid = threadIdx.x;
  int blk = blockIdx.x;
  if (blk < 4096) {                      // ---- convert ----
    int i = (blk * 256 + tid) * 4;
    float4 v = *(const float4*)(hidden + i);
    ushort4 o;
    o.x = f2bf_bits(v.x); o.y = f2bf_bits(v.y);
    o.z = f2bf_bits(v.z); o.w = f2bf_bits(v.w);
    *(ushort4*)(Xbf + i) = o;
    return;
  }
  if (blk < 4736) {                      // ---- weight pack ----
    int b = blk - 4096;
    const float* W; unsigned short* Wt; int Nsrc, n_off, bx, by;
    if (b < 256)      { W = wq; Wt = Wqkvt; Nsrc = 1024; n_off = 0;    bx = b & 15;         by = b >> 4; }
    else if (b < 320) { W = wk; Wt = Wqkvt; Nsrc = 256;  n_off = 1024; bx = (b - 256) & 3;  by = (b - 256) >> 2; }
    else if (b < 384) { W = wv; Wt = Wqkvt; Nsrc = 256;  n_off = 1280; bx = (b - 320) & 3;  by = (b - 320) >> 2; }
    else              { W = wo; Wt = Wot;   Nsrc = 1024; n_off = 0;    bx = (b - 384) & 15; by = (b - 384) >> 4; }
    const int tn = bx * 64, tk = by * 64;
    for (int e = tid; e < 4096; e += 256) {
      int kk = e >> 6, nn = e & 63;
      T[nn][kk] = f2bf_bits(W[(size_t)(tk + kk) * Nsrc + tn + nn]);
    }
    __syncthreads();
    for (int e = tid; e < 4096; e += 256) {
      int nn = e >> 6, kk = e & 63;
      Wt[(size_t)(n_off + tn + nn) * 1024 + tk + kk] = T[nn][kk];
    }
    return;
  }
  {                                      // ---- mask bitmap + per-tile max ----
    int mb = blk - 4736;
    const int bx = mb & 31, by = mb >> 5;
    const int bq = by * 64, bk = bx * 64, w = tid >> 6;
    bool nz = false;
    float vmax = -INFINITY;
    #pragma unroll
    for (int i = 0; i < 4; ++i) {
      int e = (i * 256 + tid) * 4;
      int r = e >> 6, c = e & 63;
      float4 v = *(const float4*)(mask + (size_t)(bq + r) * 2048 + bk + c);
      nz |= (v.x != 0.f) | (v.y != 0.f) | (v.z != 0.f) | (v.w != 0.f);
      vmax = fmaxf(vmax, fmaxf(fmaxf(v.x, v.y), fmaxf(v.z, v.w)));
    }
    #pragma unroll
    for (int m = 1; m < 64; m <<= 1) vmax = fmaxf(vmax, __shfl_xor(vmax, m, 64));
    unsigned long long anynz = __ballot((int)nz);
    __shared__ float wm[4];
    __shared__ int wf[4];
    if ((tid & 63) == 0) { wm[w] = vmax; wf[w] = (anynz != 0ull); }
    __syncthreads();
    if (tid == 0) {
      int idx = by * 32 + bx;
      flags[idx] = wf[0] | wf[1] | wf[2] | wf[3];
      tmax[idx] = fmaxf(fmaxf(wm[0], wm[1]), fmaxf(wm[2], wm[3]));
    }
  }
}

// ---- transpose V with sigma-permutation within each 64-block (zero-shuffle PV, 16x16):
//      k = 16n+4g+j  ->  k' = 32*(n>>1) + 8g + 4*(n&1) + j
__global__ __launch_bounds__(256) void transpose_v(
    const unsigned short* __restrict__ qkv, unsigned short* __restrict__ vt) {
  __shared__ unsigned short T[64][72];
  const int tid = threadIdx.x;
  const int st = blockIdx.x * 64, bk = blockIdx.y;      // bk = b*4+kvh
  const int b = bk >> 2, kvh = bk & 3;
  const unsigned short* src = qkv + (size_t)(b * 2048 + st) * 1536 + 1280 + kvh * 64;
  for (int e = tid; e < 4096; e += 256) {
    int s = e >> 6, d = e & 63;
    T[d][s] = src[(size_t)s * 1536 + d];                // coalesced read
  }
  __syncthreads();
  unsigned short* dst = vt + (size_t)bk * 64 * 2048 + st;
  for (int e = tid; e < 4096; e += 256) {
    int d = e >> 6, s = e & 63;
    int p = ((s >> 5) << 5) | (((s >> 2) & 3) << 3) | (((s >> 4) & 1) << 2) | (s & 3);
    dst[(size_t)d * 2048 + p] = T[d][s];                // 128B-contained permute
  }
}

// ------- bf16 GEMM (BM=64, BN template, BK=64): dbuf single-barrier staging;
//         conflict-free swizzle; XCD-swizzled; static buffer parity via unroll 2 -------
template <bool OUT_BF16, bool QKNORM, int BN>
__global__ __launch_bounds__(256) void gemm_bt(
    const unsigned short* __restrict__ A, const unsigned short* __restrict__ Bt,
    void* __restrict__ Cp, int M, int N, int K, int ldc,
    const float* __restrict__ qw, const float* __restrict__ kw) {
  constexpr int BROUNDS = BN / 32;            // B staging rounds (256 chunks each)
  constexpr int NR = BN / 32;                 // B frags per wave per kd
  __shared__ unsigned short As[2][64 * 64];   // 8 KB x2
  __shared__ unsigned short Bs[2][BN * 64];   // BN/8 KB x2
  const int tid = threadIdx.x;
  const int w = tid >> 6, l = tid & 63, lr = l & 15, lg = l >> 4;
  const int nwg = gridDim.x * gridDim.y;
  int orig = blockIdx.y * gridDim.x + blockIdx.x;
  int wgid = ((nwg & 7) == 0) ? ((orig & 7) * (nwg >> 3) + (orig >> 3)) : orig;
  const int bm = (wgid / gridDim.x) * 64, bn = (wgid % gridDim.x) * BN;
  const int wrow = (w >> 1) * 32, wcol = (w & 1) * (BN / 2);   // wave: 32 rows x BN/2 cols

  // per-lane staged-source pointers (advance by BK elements per stage call)
  const int rthr = tid >> 3;                      // 0..31
  const int qsw = (tid & 7) ^ (rthr & 7);         // lane-constant swizzled chunk
  const unsigned short* srcA[2];
  const unsigned short* srcB[BROUNDS];
  #pragma unroll
  for (int it = 0; it < 2; ++it)
    srcA[it] = A + (size_t)(bm + it * 32 + rthr) * K + qsw * 8;
  #pragma unroll
  for (int it = 0; it < BROUNDS; ++it)
    srcB[it] = Bt + (size_t)(bn + it * 32 + rthr) * K + qsw * 8;

  auto stage = [&](int bi) {
    #pragma unroll
    for (int it = 0; it < 2; ++it) {
      async16(&As[bi][it * 2048 + w * 512], srcA[it]);
      srcA[it] += 64;
    }
    #pragma unroll
    for (int it = 0; it < BROUNDS; ++it) {
      async16(&Bs[bi][it * 2048 + w * 512], srcB[it]);
      srcB[it] += 64;
    }
  };

  stage(0);

  f32x4_t acc[2][NR] = {};
  const int nst = K >> 6;

  #pragma unroll 2
  for (int st = 0; st < nst; ++st) {
    __syncthreads();   // drains vmcnt: buf[cur] ready; all waves done reading buf[cur^1]
    if (st + 1 < nst) stage((st + 1) & 1);
    const int cur = st & 1;
    #pragma unroll
    for (int kd = 0; kd < 2; ++kd) {
      short8_t af[2], bfr[NR];
      #pragma unroll
      for (int m = 0; m < 2; ++m) {
        int r = wrow + m * 16 + lr;
        af[m] = *(const short8_t*)(&As[cur][r * 64 + ((kd * 4 + lg) ^ (r & 7)) * 8]);
      }
      #pragma unroll
      for (int n = 0; n < NR; ++n) {
        int r = wcol + n * 16 + lr;
        bfr[n] = *(const short8_t*)(&Bs[cur][r * 64 + ((kd * 4 + lg) ^ (r & 7)) * 8]);
      }
      #pragma unroll
      for (int m = 0; m < 2; ++m)
        #pragma unroll
        for (int n = 0; n < NR; ++n)
          acc[m][n] = __builtin_amdgcn_mfma_f32_16x16x32_bf16(af[m], bfr[n], acc[m][n], 0, 0, 0);
    }
  }

  if constexpr (QKNORM) {
    static_assert(!QKNORM || BN == 128, "QKNORM requires 64-col wave spans");
    int seg = (bn + wcol) >> 6;               // wave holds full 64-col head segment
    if (seg < 20) {
      const float* wseg = (seg < 16) ? qw : kw;
      float wv[4];
      #pragma unroll
      for (int n = 0; n < 4; ++n) {
        wv[n] = wseg[n * 16 + lr];
        if (seg < 16) wv[n] *= 0.125f;
      }
      #pragma unroll
      for (int m = 0; m < 2; ++m)
        #pragma unroll
        for (int j = 0; j < 4; ++j) {
          float ss = acc[m][0][j] * acc[m][0][j];
          #pragma unroll
          for (int n = 1; n < 4; ++n) ss += acc[m][n][j] * acc[m][n][j];
          #pragma unroll
          for (int x = 1; x < 16; x <<= 1) ss += __shfl_xor(ss, x, 64);
          float rinv = rsqrtf(ss * (1.0f / 64.0f) + 1e-6f);
          #pragma unroll
          for (int n = 0; n < 4; ++n) acc[m][n][j] *= rinv * wv[n];
        }
    }
  }

  #pragma unroll
  for (int m = 0; m < 2; ++m)
    #pragma unroll
    for (int n = 0; n < NR; ++n)
      #pragma unroll
      for (int j = 0; j < 4; ++j) {
        int row = bm + wrow + m * 16 + lg * 4 + j;
        int col = bn + wcol + n * 16 + lr;
        float v = acc[m][n][j];
        if (OUT_BF16) ((unsigned short*)Cp)[(size_t)row * ldc + col] = f2bf_bits(v);
        else          ((float*)Cp)[(size_t)row * ldc + col] = v;
      }
}

// ------- flash attention (R18 proven, 69.4us): frozen; kt loop unrolled 2x for
//         static buffer parity -------
__global__ __launch_bounds__(256, 4) void flash_attn(
    const unsigned short* __restrict__ qkv, const unsigned short* __restrict__ vtg,
    const float* __restrict__ mask, const int* __restrict__ flags,
    const float* __restrict__ tmax, const float* __restrict__ qw,
    const float* __restrict__ kw, unsigned short* __restrict__ O) {
  // grid is 32x32 = 1024 blocks; swizzle so each XCD gets 4 consecutive bh strips
  int orig = blockIdx.y * 32 + blockIdx.x;
  int swz = (orig & 7) * 128 + (orig >> 3);
  const int qt = swz & 31, bh = swz >> 5;
  const int b = bh >> 4, hq = bh & 15, kvh = hq >> 2;
  const int tid = threadIdx.x, w = tid >> 6, l = tid & 63, lr = l & 15, lg = l >> 4;

  // linear LDS + XOR swizzle (16B units): LDS(row, cc) holds global(row, cc ^ (row&7))
  __shared__ unsigned short Ks[2][64 * 64];   // [k][d]   8KB x2
  __shared__ unsigned short Vs[2][64 * 64];   // [d][k']  8KB x2 (k' sigma-permuted)

  const unsigned short* Qg = qkv + (size_t)(b * 2048 + qt * 64) * 1536 + hq * 64;
  const unsigned short* Kg = qkv + (size_t)(b * 2048) * 1536 + 1024 + kvh * 64;
  const unsigned short* Vg = vtg + (size_t)(b * 4 + kvh) * 64 * 2048;
  const float* Mg = mask + (size_t)(qt * 64) * 2048;
  const int* Fp = flags + qt * 32;

  auto stage = [&](int kt2, int bi) {
    #pragma unroll
    for (int it = 0; it < 2; ++it) {
      int c = it * 256 + tid;                    // 16B chunk id 0..511
      int r = c >> 3, cc = (c & 7) ^ (r & 7);    // pre-swizzled source column
      async16(&Ks[bi][it * 2048 + w * 512],
              Kg + (size_t)(kt2 * 64 + r) * 1536 + cc * 8);
      async16(&Vs[bi][it * 2048 + w * 512],
              Vg + (size_t)r * 2048 + kt2 * 64 + cc * 8);
    }
  };

  stage(0, 0);

  // a-priori bound: s <= 8*max_d|qw_d*kw_d| (Cauchy-Schwarz on RMS-normalized q,k with
  // the 0.125 scale folded into qw) + max over this strip's mask tiles.
  const float L2E = 1.44269504f;
  float pmax = fabsf(qw[l] * kw[l]);
  #pragma unroll
  for (int m = 1; m < 64; m <<= 1) pmax = fmaxf(pmax, __shfl_xor(pmax, m, 64));
  float tmx = (l < 32) ? tmax[qt * 32 + l] : -INFINITY;
  #pragma unroll
  for (int m = 1; m < 64; m <<= 1) tmx = fmaxf(tmx, __shfl_xor(tmx, m, 64));
  const float nm = -(8.0f * pmax + fmaxf(tmx, 0.0f)) * L2E;

  // Q fragments straight from global (once per block): wave w owns rows w*16..w*16+15
  short8_t qf[2];
  {
    const unsigned short* qrow = Qg + (size_t)(w * 16 + lr) * 1536 + lg * 8;
    qf[0] = *(const short8_t*)(qrow);
    qf[1] = *(const short8_t*)(qrow + 32);
  }

  // constant ones B-fragment: col 0 = 1.0 -> sum column
  short8_t vb1;
  #pragma unroll
  for (int e = 0; e < 8; ++e) vb1[e] = (lr == 0) ? (short)0x3f80 : (short)0;

  f32x4_t oacc[5] = {};                          // [0..3]=O cols, [4]=row-sum col

  #pragma unroll 2
  for (int kt = 0; kt < 32; ++kt) {
    __syncthreads();                             // buf ready (vmcnt drained), prev reads done
    if (kt < 31) stage(kt + 1, (kt + 1) & 1);
    const int cur = kt & 1;

    // S^T = K Q^T (swapped operands; scale pre-folded into Q).
    // sacc[n][j] = S[k = kt*64 + n*16 + lg*4 + j][q = qt*64 + w*16 + lr]
    f32x4_t sacc[4] = {};
    __builtin_amdgcn_s_setprio(1);
    #pragma unroll
    for (int kd = 0; kd < 2; ++kd)
      #pragma unroll
      for (int n = 0; n < 4; ++n) {
        int kr = n * 16 + lr;
        short8_t kf = *(const short8_t*)(&Ks[cur][kr * 64 + ((kd * 4 + lg) ^ (kr & 7)) * 8]);
        sacc[n] = __builtin_amdgcn_mfma_f32_16x16x32_bf16(kf, qf[kd], sacc[n], 0, 0, 0);
      }
    __builtin_amdgcn_s_setprio(0);

    // exp straight off sacc (fixed bound): lane holds P[q=lr][k=16n+4lg+j] -> exactly the
    // PV A-frag at k' = 32*(n>>1) + 8*lg + 4*(n&1) + j (V was sigma-permuted to match).
    const bool hasmask = Fp[kt] != 0;
    float e4[4][4];
    #pragma unroll
    for (int n = 0; n < 4; ++n) {
      if (hasmask) {
        float4 mv = *(const float4*)(Mg + (size_t)(w * 16 + lr) * 2048 + kt * 64 + n * 16 + lg * 4);
        e4[n][0] = exp2f(fmaf(sacc[n][0] + mv.x, L2E, nm));
        e4[n][1] = exp2f(fmaf(sacc[n][1] + mv.y, L2E, nm));
        e4[n][2] = exp2f(fmaf(sacc[n][2] + mv.z, L2E, nm));
        e4[n][3] = exp2f(fmaf(sacc[n][3] + mv.w, L2E, nm));
      } else {
        #pragma unroll
        for (int j = 0; j < 4; ++j)
          e4[n][j] = exp2f(fmaf(sacc[n][j], L2E, nm));
      }
    }
    short8_t pa[2];
    #pragma unroll
    for (int kd = 0; kd < 2; ++kd) {
      int4 pk;
      pk.x = (int)cvt_pk_bf16(e4[2 * kd][0],     e4[2 * kd][1]);
      pk.y = (int)cvt_pk_bf16(e4[2 * kd][2],     e4[2 * kd][3]);
      pk.z = (int)cvt_pk_bf16(e4[2 * kd + 1][0], e4[2 * kd + 1][1]);
      pk.w = (int)cvt_pk_bf16(e4[2 * kd + 1][2], e4[2 * kd + 1][3]);
      pa[kd] = *(short8_t*)&pk;
    }

    // O += P V (+ ones column -> running sum); zero-shuffle A-frags
    __builtin_amdgcn_s_setprio(1);
    #pragma unroll
    for (int kd = 0; kd < 2; ++kd) {
      #pragma unroll
      for (int nd = 0; nd < 4; ++nd) {
        int vr = nd * 16 + lr;
        short8_t vb = *(const short8_t*)(&Vs[cur][vr * 64 + ((kd * 4 + lg) ^ (vr & 7)) * 8]);
        oacc[nd] = __builtin_amdgcn_mfma_f32_16x16x32_bf16(pa[kd], vb, oacc[nd], 0, 0, 0);
      }
      oacc[4] = __builtin_amdgcn_mfma_f32_16x16x32_bf16(pa[kd], vb1, oacc[4], 0, 0, 0);
    }
    __builtin_amdgcn_s_setprio(0);
  }

  // epilogue: O[q = qt*64 + w*16 + lg*4 + j][d = hq*64 + nd*16 + lr]; sums in lanes lr==0
  float rln[4];
  #pragma unroll
  for (int j = 0; j < 4; ++j) rln[j] = 1.0f / __shfl(oacc[4][j], l & 48, 64);
  #pragma unroll
  for (int nd = 0; nd < 4; ++nd)
    #pragma unroll
    for (int j = 0; j < 4; ++j) {
      size_t row = (size_t)(b * 2048 + qt * 64 + w * 16 + lg * 4 + j);
      O[row * 1024 + hq * 64 + nd * 16 + lr] = f2bf_bits(oacc[nd][j] * rln[j]);
    }
}

extern "C" void kernel_launch(void* const* d_in, const int* in_sizes, int n_in,
                              void* d_out, int out_size, void* d_ws, size_t ws_size,
                              hipStream_t stream) {
  const float* hidden = (const float*)d_in[0];
  const float* mask   = (const float*)d_in[1];
  const float* wq     = (const float*)d_in[2];
  const float* wk     = (const float*)d_in[3];
  const float* wv     = (const float*)d_in[4];
  const float* wo     = (const float*)d_in[5];
  const float* qw     = (const float*)d_in[6];
  const float* kw     = (const float*)d_in[7];

  char* ws = (char*)d_ws;
  unsigned short* Xbf   = (unsigned short*)(ws);              // [4096][1024] bf16
  unsigned short* Wqkvt = (unsigned short*)(ws +  8388608);   // [1536][1024] bf16 (dead after gemm1)
  unsigned short* Wot   = (unsigned short*)(ws + 11534336);   // [1024][1024] bf16
  unsigned short* QKV   = (unsigned short*)(ws + 13631488);   // [4096][1536] bf16
  unsigned short* Vtg   = Wqkvt;                              // [8*64][2048] bf16 (ends 10485760)
  unsigned short* Obf   = Xbf;                                // X dead after gemm1

  // flags/tmax in the TAIL of d_out: written by prep, read by flash, then gemm2
  // overwrites all of d_out last.
  char* dtail = (char*)d_out + (size_t)out_size * 4 - 8192;
  int*   flags = (int*)dtail;                                 // [1024]
  float* tmaxb = (float*)(dtail + 4096);                      // [1024]

  prep<<<5760, 256, 0, stream>>>(hidden, Xbf, wq, wk, wv, wo, Wqkvt, Wot, mask, flags, tmaxb);

  gemm_bt<true, true, 128><<<dim3(12, 64), 256, 0, stream>>>(
      Xbf, Wqkvt, QKV, 4096, 1536, 1024, 1536, qw, kw);
  transpose_v<<<dim3(32, 8), 256, 0, stream>>>(QKV, Vtg);      // after gemm1 (aliases Wqkvt)
  flash_attn<<<dim3(32, 32), 256, 0, stream>>>(QKV, Vtg, mask, flags, tmaxb, qw, kw, Obf);
  gemm_bt<false, false, 64><<<dim3(16, 64), 256, 0, stream>>>(
      Obf, Wot, d_out, 4096, 1024, 1024, 1024, nullptr, nullptr);
}